// Round 16
// baseline (1923.717 us; speedup 1.0000x reference)
//
#include <hip/hip_runtime.h>
#include <math.h>

#define B_N 4096
#define D_F 2048
#define K_P 512
#define NGMAX 4096
#define MU 0.9f
#define OMU (1.0f - MU)
#define LOG2MU (-0.15200309344504997f)
#define FLTMAX 3.402823466e+38f
#define IMAX 0x7FFFFFFF
#define TILE 64
#define SDPITCH 513

// LDS carve (floats/ints) for scan: sdot | sgram | szn2 | sscale | sdump | ints
#define SMEM_FLOATS (64 * SDPITCH + 64 * 65 + 64 + 512 + 16)
#define SMEM_INTS (512 + 16)
#define SMEM_BYTES ((SMEM_FLOATS + SMEM_INTS) * 4)
#define DUMPIDX (64 * SDPITCH + 64 * 65 + 64 + 512)

typedef __attribute__((ext_vector_type(8))) short short8v;
typedef __attribute__((ext_vector_type(4))) float float4v;

__device__ __forceinline__ bool argless(float v1, int i1, float v2, int i2) {
    return (v1 < v2) || (v1 == v2 && i1 < i2);
}

// u32 DPP min-reduce: lane 63 holds the wave min; readlane broadcasts.
template <int CTRL>
__device__ __forceinline__ unsigned dppmin_u(unsigned v) {
    unsigned t = (unsigned)__builtin_amdgcn_update_dpp((int)v, (int)v, CTRL, 0xf, 0xf, false);
    return min(v, t);
}
__device__ __forceinline__ unsigned wave_min_u(unsigned v) {
    v = dppmin_u<0x111>(v);
    v = dppmin_u<0x112>(v);
    v = dppmin_u<0x114>(v);
    v = dppmin_u<0x118>(v);
    v = dppmin_u<0x142>(v);
    v = dppmin_u<0x143>(v);
    return (unsigned)__builtin_amdgcn_readlane((int)v, 63);
}

// -------- prep: compact gated indices, counts --------
__global__ void k_prep(const int* __restrict__ g, int* __restrict__ gsteps,
                       int* __restrict__ scal) {
    __shared__ int s[1024];
    __shared__ int base;
    int tid = threadIdx.x;
    if (tid == 0) base = 0;
    __syncthreads();
    for (int c = 0; c < 4; ++c) {
        int i = c * 1024 + tid;
        int gi = (g[i] != 0) ? 1 : 0;
        s[tid] = gi;
        __syncthreads();
        for (int off = 1; off < 1024; off <<= 1) {
            int v = (tid >= off) ? s[tid - off] : 0;
            __syncthreads();
            s[tid] += v;
            __syncthreads();
        }
        int pos = base + s[tid] - 1;
        if (gi) gsteps[pos] = i;
        __syncthreads();
        if (tid == 1023) base += s[1023];
        __syncthreads();
    }
    if (tid == 0) { scal[0] = base; scal[1] = B_N - base; }
}

// -------- fp32 -> bf16 hi/lo split (truncation; x == hi + lo + O(2^-14 x)) --------
__global__ void k_split(const float* __restrict__ src, unsigned short* __restrict__ hi,
                        unsigned short* __restrict__ lo, int n4) {
    int i = blockIdx.x * 256 + threadIdx.x;
    if (i >= n4) return;
    float4 v = ((const float4*)src)[i];
    float xs[4] = {v.x, v.y, v.z, v.w};
    unsigned short h[4], l[4];
#pragma unroll
    for (int q = 0; q < 4; ++q) {
        unsigned b = __float_as_uint(xs[q]);
        unsigned hb = b & 0xFFFF0000u;
        float lf = xs[q] - __uint_as_float(hb);
        h[q] = (unsigned short)(hb >> 16);
        l[q] = (unsigned short)(__float_as_uint(lf) >> 16);
    }
    ((ushort4*)hi)[i] = make_ushort4(h[0], h[1], h[2], h[3]);
    ((ushort4*)lo)[i] = make_ushort4(l[0], l[1], l[2], l[3]);
}

__device__ __forceinline__ void split_store(unsigned short* __restrict__ hi,
                                            unsigned short* __restrict__ lo,
                                            size_t idx, float4 v) {
    float xs[4] = {v.x, v.y, v.z, v.w};
    unsigned short h[4], l[4];
#pragma unroll
    for (int q = 0; q < 4; ++q) {
        unsigned b = __float_as_uint(xs[q]);
        unsigned hb = b & 0xFFFF0000u;
        float lf = xs[q] - __uint_as_float(hb);
        h[q] = (unsigned short)(hb >> 16);
        l[q] = (unsigned short)(__float_as_uint(lf) >> 16);
    }
    *(ushort4*)(hi + idx) = make_ushort4(h[0], h[1], h[2], h[3]);
    *(ushort4*)(lo + idx) = make_ushort4(l[0], l[1], l[2], l[3]);
}

// -------- row squared norms (wave per row) --------
__global__ void k_rownorm(const float* __restrict__ src, float* __restrict__ dst, int nrows) {
    int row = blockIdx.x * 4 + (threadIdx.x >> 6);
    int lane = threadIdx.x & 63;
    if (row >= nrows) return;
    const float* p = src + (size_t)row * D_F;
    float acc = 0.f;
    for (int d0 = lane * 4; d0 < D_F; d0 += 256) {
        float4 v = *(const float4*)(p + d0);
        acc += v.x * v.x + v.y * v.y + v.z * v.z + v.w * v.w;
    }
    for (int off = 32; off; off >>= 1) acc += __shfl_xor(acc, off);
    if (lane == 0) dst[row] = acc;
}

// -------- anomaly column sums (partials) --------
__global__ void k_colsum(const float* __restrict__ Z, const int* __restrict__ g,
                         float* __restrict__ anom_part) {
    int d = blockIdx.x * 256 + threadIdx.x;
    int rc = blockIdx.y;
    float acc = 0.f;
    int r0 = rc * 128;
    for (int r = r0; r < r0 + 128; ++r) {
        if (g[r] == 0) acc += Z[(size_t)r * D_F + d];
    }
    anom_part[(size_t)rc * D_F + d] = acc;
}

// -------- finalize m_a --------
__global__ void k_fin_ma(const float* __restrict__ anom_part, const float* __restrict__ ma_in,
                         const int* __restrict__ scal, float* __restrict__ m_a_used,
                         float* __restrict__ scal_f) {
    __shared__ float red[1024];
    int tid = threadIdx.x;
    int na = scal[1];
    float m2 = 0.f;
    for (int dd = tid; dd < D_F; dd += 1024) {
        float s = 0.f;
        for (int c = 0; c < 32; ++c) s += anom_part[(size_t)c * D_F + dd];
        float v = (na > 0) ? (s / (float)na) : ma_in[dd];
        m_a_used[dd] = v;
        m2 += v * v;
    }
    red[tid] = m2;
    __syncthreads();
    for (int off = 512; off; off >>= 1) {
        if (tid < off) red[tid] += red[tid + off];
        __syncthreads();
    }
    if (tid == 0) scal_f[0] = red[0];
}

// -------- MFMA GEMM (NT: C = A * B^T) via bf16 hi/lo split, 64x64 tile, BK=32 --------
template <int MODE>
__global__ __launch_bounds__(256)
void k_gemm_mfma(const unsigned short* __restrict__ Zhi, const unsigned short* __restrict__ Zlo,
                 const unsigned short* __restrict__ P0hi, const unsigned short* __restrict__ P0lo,
                 const unsigned short* __restrict__ Pnhi, const unsigned short* __restrict__ Pnlo,
                 const int* __restrict__ gsteps, const int* __restrict__ scal,
                 float* __restrict__ Gram, float* __restrict__ Dot, float* __restrict__ Dotf) {
    int ng = scal[0];
    int M = (MODE == 0) ? (ng + K_P) : B_N;
    int N = (MODE == 0) ? ng : K_P;
    int mb = blockIdx.y * 64, nb = blockIdx.x * 64;
    if (mb >= M || nb >= N) return;
    if (MODE == 0 && (mb + 64 <= ng) && (nb + 64 <= mb)) return;

    __shared__ __align__(16) unsigned short Ah[64][40];
    __shared__ __align__(16) unsigned short Al[64][40];
    __shared__ __align__(16) unsigned short Bh[64][40];
    __shared__ __align__(16) unsigned short Bl[64][40];
    __shared__ const unsigned short* rAh[64];
    __shared__ const unsigned short* rAl[64];
    __shared__ const unsigned short* rBh[64];
    __shared__ const unsigned short* rBl[64];

    int tid = threadIdx.x;
    if (tid < 64) {
        int gm = mb + tid;
        const unsigned short *ph = nullptr, *pl = nullptr;
        if (MODE == 0) {
            if (gm < ng) {
                size_t o = (size_t)gsteps[gm] * D_F;
                ph = Zhi + o; pl = Zlo + o;
            } else if (gm < ng + K_P) {
                size_t o = (size_t)(gm - ng) * D_F;
                ph = P0hi + o; pl = P0lo + o;
            }
        } else {
            if (gm < B_N) {
                size_t o = (size_t)gm * D_F;
                ph = Zhi + o; pl = Zlo + o;
            }
        }
        rAh[tid] = ph; rAl[tid] = pl;
    } else if (tid < 128) {
        int t = tid - 64;
        int gn = nb + t;
        const unsigned short *ph = nullptr, *pl = nullptr;
        if (MODE == 0) {
            if (gn < ng) {
                size_t o = (size_t)gsteps[gn] * D_F;
                ph = Zhi + o; pl = Zlo + o;
            }
        } else {
            if (gn < K_P) {
                size_t o = (size_t)gn * D_F;
                ph = Pnhi + o; pl = Pnlo + o;
            }
        }
        rBh[t] = ph; rBl[t] = pl;
    }
    __syncthreads();

    int lrow = tid >> 2, lk = (tid & 3) * 8;
    const unsigned short* pah = rAh[lrow];
    const unsigned short* pal = rAl[lrow];
    const unsigned short* pbh = rBh[lrow];
    const unsigned short* pbl = rBl[lrow];

    int wave = tid >> 6, lane = tid & 63;
    int wr = (wave >> 1) * 32, wc = (wave & 1) * 32;
    int fr = lane & 15, kg = lane >> 4;

    float4v acc00 = {0.f, 0.f, 0.f, 0.f}, acc01 = {0.f, 0.f, 0.f, 0.f};
    float4v acc10 = {0.f, 0.f, 0.f, 0.f}, acc11 = {0.f, 0.f, 0.f, 0.f};
    const int4 z4i = make_int4(0, 0, 0, 0);

    for (int k0 = 0; k0 < D_F; k0 += 32) {
        int4 vah = pah ? *(const int4*)(pah + k0 + lk) : z4i;
        int4 val = pal ? *(const int4*)(pal + k0 + lk) : z4i;
        int4 vbh = pbh ? *(const int4*)(pbh + k0 + lk) : z4i;
        int4 vbl = pbl ? *(const int4*)(pbl + k0 + lk) : z4i;
        __syncthreads();
        *(int4*)&Ah[lrow][lk] = vah;
        *(int4*)&Al[lrow][lk] = val;
        *(int4*)&Bh[lrow][lk] = vbh;
        *(int4*)&Bl[lrow][lk] = vbl;
        __syncthreads();

        short8v ah0 = *(const short8v*)&Ah[wr + fr][kg * 8];
        short8v ah1 = *(const short8v*)&Ah[wr + 16 + fr][kg * 8];
        short8v al0 = *(const short8v*)&Al[wr + fr][kg * 8];
        short8v al1 = *(const short8v*)&Al[wr + 16 + fr][kg * 8];
        short8v bh0 = *(const short8v*)&Bh[wc + fr][kg * 8];
        short8v bh1 = *(const short8v*)&Bh[wc + 16 + fr][kg * 8];
        short8v bl0 = *(const short8v*)&Bl[wc + fr][kg * 8];
        short8v bl1 = *(const short8v*)&Bl[wc + 16 + fr][kg * 8];

        acc00 = __builtin_amdgcn_mfma_f32_16x16x32_bf16(ah0, bh0, acc00, 0, 0, 0);
        acc00 = __builtin_amdgcn_mfma_f32_16x16x32_bf16(ah0, bl0, acc00, 0, 0, 0);
        acc00 = __builtin_amdgcn_mfma_f32_16x16x32_bf16(al0, bh0, acc00, 0, 0, 0);

        acc01 = __builtin_amdgcn_mfma_f32_16x16x32_bf16(ah0, bh1, acc01, 0, 0, 0);
        acc01 = __builtin_amdgcn_mfma_f32_16x16x32_bf16(ah0, bl1, acc01, 0, 0, 0);
        acc01 = __builtin_amdgcn_mfma_f32_16x16x32_bf16(al0, bh1, acc01, 0, 0, 0);

        acc10 = __builtin_amdgcn_mfma_f32_16x16x32_bf16(ah1, bh0, acc10, 0, 0, 0);
        acc10 = __builtin_amdgcn_mfma_f32_16x16x32_bf16(ah1, bl0, acc10, 0, 0, 0);
        acc10 = __builtin_amdgcn_mfma_f32_16x16x32_bf16(al1, bh0, acc10, 0, 0, 0);

        acc11 = __builtin_amdgcn_mfma_f32_16x16x32_bf16(ah1, bh1, acc11, 0, 0, 0);
        acc11 = __builtin_amdgcn_mfma_f32_16x16x32_bf16(ah1, bl1, acc11, 0, 0, 0);
        acc11 = __builtin_amdgcn_mfma_f32_16x16x32_bf16(al1, bh1, acc11, 0, 0, 0);
    }

#pragma unroll
    for (int fm = 0; fm < 2; ++fm) {
#pragma unroll
        for (int i = 0; i < 4; ++i) {
            int grow = mb + wr + fm * 16 + kg * 4 + i;
            if (grow >= M) continue;
            float* crow;
            if (MODE == 0)
                crow = (grow < ng) ? (Gram + (size_t)grow * NGMAX)
                                   : (Dot + (size_t)(grow - ng) * NGMAX);
            else
                crow = Dotf + (size_t)grow * K_P;
#pragma unroll
            for (int fn = 0; fn < 2; ++fn) {
                int gcol = nb + wc + fn * 16 + fr;
                if (gcol >= N) continue;
                float v;
                if (fm == 0 && fn == 0) v = acc00[i];
                else if (fm == 0 && fn == 1) v = acc01[i];
                else if (fm == 1 && fn == 0) v = acc10[i];
                else v = acc11[i];
                crow[gcol] = v;
            }
        }
    }
}

// -------- tiled sequential scan: branchless phase S --------
__global__ __launch_bounds__(512, 1)
void k_scan_tiled(const float* __restrict__ Gram, const float* __restrict__ Dot,
                  const float* __restrict__ pn2_0, const float* __restrict__ zn2,
                  const int* __restrict__ gsteps, const int* __restrict__ scal,
                  int* __restrict__ winlist, int* __restrict__ clist,
                  int* __restrict__ cnt_out) {
    extern __shared__ char smem_raw[];
    float* sdot = (float*)smem_raw;             // [64][SDPITCH] transposed: sdot[x][k]
    float* sgram = sdot + 64 * SDPITCH;         // [64][65]
    float* szn2 = sgram + 64 * 65;              // [64]
    float* sscale = szn2 + 64;                  // [512] mu^rowcnt per row
    // sdot[DUMPIDX .. DUMPIDX+15] = dump scratch for dead RMW traffic
    int* rowcnt = (int*)(sdot + SMEM_FLOATS);   // [512]
    int* listlen = rowcnt + 512;                // [8]

    int tid = threadIdx.x;
    int lane = tid & 63;
    int wave = tid >> 6;
    int ng = scal[0];

    rowcnt[tid] = 0;
    if (tid < 8) listlen[tid] = 0;
    __syncthreads();

    // wave-0 lane-private state: lane owns prototypes k = r*64 + lane
    float pn2r[8];
    unsigned idxp[8];
    if (wave == 0) {
#pragma unroll
        for (int r = 0; r < 8; ++r) {
            pn2r[r] = pn2_0[r * 64 + lane];
            idxp[r] = (unsigned)((r << 6) | lane);
        }
    }

    int ntiles = (ng + TILE - 1) / TILE;
    for (int T = 0; T < ntiles; ++T) {
        int j0 = T * TILE;
        int tlen = min(TILE, ng - j0);

        // per-row scale (same-wave write/read: thread tid serves wave tid>>6)
        sscale[tid] = exp2f((float)rowcnt[tid] * LOG2MU);

        // ---- stage Dot0 tile (transposed) with mu^c scale fused ----
        {
            const float* basep = Dot + (size_t)(wave * 64) * NGMAX + j0 + lane;
            float* sb = sdot + lane * SDPITCH + wave * 64;
            const float* ss = sscale + wave * 64;
#pragma unroll 16
            for (int rr = 0; rr < 64; ++rr) {
                sb[rr] = basep[(size_t)rr * NGMAX] * ss[rr];
            }
        }
        // ---- corrections: wave streams its own flat list, batched (MLP=8) ----
        {
            int len = listlen[wave];
            const int* cl = clist + (size_t)wave * NGMAX;
            int i = 0;
            for (; i + 8 <= len; i += 8) {
                int a[8];
#pragma unroll
                for (int q = 0; q < 8; ++q) a[q] = cl[i + q];
                float gv[8];
#pragma unroll
                for (int q = 0; q < 8; ++q) {
                    int t = (a[q] >> 20) & 4095;
                    gv[q] = Gram[(size_t)t * NGMAX + j0 + lane];
                }
#pragma unroll
                for (int q = 0; q < 8; ++q) {
                    int row = a[q] & 511;
                    int gq = (a[q] >> 9) & 2047;
                    int c = rowcnt[row];
                    float wq = OMU * exp2f((float)(c - 1 - gq) * LOG2MU);
                    sdot[lane * SDPITCH + row] += wq * gv[q];
                }
            }
            for (; i < len; ++i) {
                int a = cl[i];
                int row = a & 511;
                int gq = (a >> 9) & 2047;
                int t = (a >> 20) & 4095;
                int c = rowcnt[row];
                float wqs = OMU * exp2f((float)(c - 1 - gq) * LOG2MU);
                float gv = Gram[(size_t)t * NGMAX + j0 + lane];
                sdot[lane * SDPITCH + row] += wqs * gv;
            }
        }
        // gram diag block + zn2
        {
            int t = tid >> 3, xo = (tid & 7) * 8;
            const float* src = Gram + (size_t)(j0 + t) * NGMAX + j0 + xo;
            float4 a = *(const float4*)(src);
            float4 b = *(const float4*)(src + 4);
            float* dst = sgram + t * 65 + xo;
            dst[0] = a.x; dst[1] = a.y; dst[2] = a.z; dst[3] = a.w;
            dst[4] = b.x; dst[5] = b.y; dst[6] = b.z; dst[7] = b.w;
        }
        if (tid < TILE) {
            szn2[tid] = (tid < tlen) ? zn2[gsteps[j0 + tid]] : 0.f;
        }
        __syncthreads();

        // ---- phase S (wave 0 only): fully branchless loop body ----
        if (wave == 0) {
            float d8[8];
#pragma unroll
            for (int r = 0; r < 8; ++r) d8[r] = sdot[r * 64 + lane];  // col 0
            float z2c = szn2[0];
            float gnc = sgram[1];
            int stw_reg = 0;
            int pend_addr = DUMPIDX;
            float pend_old = 0.f, pend_g = 0.f;

            for (int jl = 0; jl < tlen; ++jl) {
                // (0) flush previous step's RMW write (unconditional; DUMP eats dead)
                sdot[pend_addr] = MU * pend_old + OMU * pend_g;

                // (1) prefetch next column + scalars (clamped selects, no branches)
                int jn = (jl + 1 < tlen) ? (jl + 1) : (tlen - 1);
                const float* cb = sdot + jn * SDPITCH;
                float pv[8];
#pragma unroll
                for (int r = 0; r < 8; ++r) pv[r] = cb[r * 64 + lane];
                float nz2 = szn2[jn];
                float ngn = sgram[jn * 65 + ((jn + 1 < 64) ? jn + 1 : 64)];
                int xr = jl + 2 + lane;
                float grmw = sgram[jl * 65 + ((xr <= 64) ? xr : 64)];

                // (2) packed-key argmin
                unsigned kk[8];
#pragma unroll
                for (int r = 0; r < 8; ++r) {
                    float v = (pn2r[r] + z2c) - 2.f * d8[r];
                    kk[r] = (__float_as_uint(v) & 0xFFFFFE00u) | idxp[r];
                }
                unsigned a01 = min(kk[0], kk[1]), a23 = min(kk[2], kk[3]);
                unsigned a45 = min(kk[4], kk[5]), a67 = min(kk[6], kk[7]);
                unsigned km = wave_min_u(min(min(a01, a23), min(a45, a67)));
                int ks = (int)(km & 511u);
                int wlane = ks & 63, wr = ks >> 6;

                // (3) unconditional RMW read (dead lanes hit DUMP)
                int rmw_addr = (xr < tlen) ? (xr * SDPITCH + ks) : DUMPIDX;
                float rmw_old = sdot[rmw_addr];

                stw_reg = (lane == jl) ? ks : stw_reg;

                // (4) select-based winner fixups (no exec-mask manipulation)
                bool mine = (lane == wlane);
                float cterm = 2.f * MU * OMU;
#pragma unroll
                for (int r = 0; r < 8; ++r) {
                    bool sel = mine && (r == wr);
                    float np = MU * MU * pn2r[r] + cterm * d8[r] + OMU * OMU * z2c;
                    pn2r[r] = sel ? np : pn2r[r];
                    float fv = MU * pv[r] + OMU * gnc;
                    pv[r] = sel ? fv : pv[r];
                }

                // shift register pipeline
#pragma unroll
                for (int r = 0; r < 8; ++r) d8[r] = pv[r];
                z2c = nz2; gnc = ngn;

                // (5) arm deferred write
                pend_addr = rmw_addr;
                pend_old = rmw_old;
                pend_g = grmw;
            }
            sdot[pend_addr] = MU * pend_old + OMU * pend_g;

            // ---- post-pass: ranks, winlist append, per-wave correction lists ----
            int wj = stw_reg;
            bool valid = (lane < tlen);
            int myL = wj >> 6;
            int rank = 0, mrow = 0, lpos = 0, lcnt = 0;
            for (int i = 0; i < tlen; ++i) {
                int wi = __builtin_amdgcn_readlane(wj, i);
                if (valid && wi == wj) {
                    mrow++;
                    if (i < lane) rank++;
                }
                if (valid && (wi >> 6) == myL) {
                    lcnt++;
                    if (i < lane) lpos++;
                }
            }
            bool first = valid && (rank == 0);
            bool firstL = valid && (lpos == 0);
            int base = rowcnt[wj];
            int lbase = listlen[myL];
            if (valid) {
                int gq = base + rank;
                winlist[(size_t)wj * NGMAX + gq] = j0 + lane;
                clist[(size_t)myL * NGMAX + lbase + lpos] =
                    wj | (gq << 9) | ((j0 + lane) << 20);
            }
            if (first) rowcnt[wj] += mrow;
            if (firstL) listlen[myL] += lcnt;
        }
        __syncthreads();
    }

    cnt_out[tid] = rowcnt[tid];
}

// -------- materialize final prototypes via win lists (block per prototype) --------
__global__ void k_mat(const float* __restrict__ Z, const float* __restrict__ P0,
                      const int* __restrict__ gsteps, const int* __restrict__ winlist,
                      const int* __restrict__ cnt, float* __restrict__ Pn,
                      unsigned short* __restrict__ Pnhi, unsigned short* __restrict__ Pnlo) {
    int k = blockIdx.x;
    int tid = threadIdx.x;
    int c = cnt[k];
    float bw = exp2f((float)c * LOG2MU);
    const float4* p0r = (const float4*)(P0 + (size_t)k * D_F);
    float4 a0 = p0r[tid], a1 = p0r[tid + 256];
    a0.x *= bw; a0.y *= bw; a0.z *= bw; a0.w *= bw;
    a1.x *= bw; a1.y *= bw; a1.z *= bw; a1.w *= bw;
    const int* wl = winlist + (size_t)k * NGMAX;
    float w = OMU;
    for (int q = c - 1; q >= 0; --q) {
        int t = wl[q];
        const float4* zr = (const float4*)(Z + (size_t)gsteps[t] * D_F);
        float4 z0 = zr[tid], z1 = zr[tid + 256];
        a0.x += w * z0.x; a0.y += w * z0.y; a0.z += w * z0.z; a0.w += w * z0.w;
        a1.x += w * z1.x; a1.y += w * z1.y; a1.z += w * z1.z; a1.w += w * z1.w;
        w *= MU;
    }
    float4* pnr = (float4*)(Pn + (size_t)k * D_F);
    pnr[tid] = a0;
    pnr[tid + 256] = a1;
    split_store(Pnhi, Pnlo, (size_t)k * D_F + (size_t)tid * 4, a0);
    split_store(Pnhi, Pnlo, (size_t)k * D_F + (size_t)(tid + 256) * 4, a1);
}

// -------- top-3 nearest + pull-loss row sums (wave per row) --------
__global__ void k_top3(const float* __restrict__ Dotf, const float* __restrict__ pn2f,
                       const float* __restrict__ Z, const float* __restrict__ Pn,
                       float* __restrict__ rowsum) {
    int row = blockIdx.x * 4 + (threadIdx.x >> 6);
    int lane = threadIdx.x & 63;
    float bv0 = FLTMAX, bv1 = FLTMAX, bv2 = FLTMAX;
    int bi0 = IMAX, bi1 = IMAX, bi2 = IMAX;
    for (int t = 0; t < 8; ++t) {
        int k = lane + 64 * t;
        float v = pn2f[k] - 2.f * Dotf[(size_t)row * K_P + k];
        if (argless(v, k, bv0, bi0)) {
            bv2 = bv1; bi2 = bi1; bv1 = bv0; bi1 = bi0; bv0 = v; bi0 = k;
        } else if (argless(v, k, bv1, bi1)) {
            bv2 = bv1; bi2 = bi1; bv1 = v; bi1 = k;
        } else if (argless(v, k, bv2, bi2)) {
            bv2 = v; bi2 = k;
        }
    }
    for (int off = 32; off; off >>= 1) {
        float a0 = bv0, a1 = bv1, a2 = bv2;
        int x0 = bi0, x1 = bi1, x2 = bi2;
        float b0 = __shfl_xor(bv0, off), b1 = __shfl_xor(bv1, off), b2 = __shfl_xor(bv2, off);
        int y0 = __shfl_xor(bi0, off), y1 = __shfl_xor(bi1, off), y2 = __shfl_xor(bi2, off);
        float nv[3]; int ni[3];
#pragma unroll
        for (int s = 0; s < 3; ++s) {
            bool ta = argless(a0, x0, b0, y0);
            nv[s] = ta ? a0 : b0;
            ni[s] = ta ? x0 : y0;
            if (ta) { a0 = a1; x0 = x1; a1 = a2; x1 = x2; a2 = FLTMAX; x2 = IMAX; }
            else    { b0 = b1; y0 = y1; b1 = b2; y1 = y2; b2 = FLTMAX; y2 = IMAX; }
        }
        bv0 = nv[0]; bv1 = nv[1]; bv2 = nv[2];
        bi0 = ni[0]; bi1 = ni[1]; bi2 = ni[2];
    }
    const float* pa = Pn + (size_t)bi0 * D_F;
    const float* pb = Pn + (size_t)bi1 * D_F;
    const float* pc = Pn + (size_t)bi2 * D_F;
    const float* zr = Z + (size_t)row * D_F;
    const float third = 1.f / 3.f;
    float acc = 0.f;
    for (int d0 = lane * 4; d0 < D_F; d0 += 256) {
        float4 z = *(const float4*)(zr + d0);
        float4 A = *(const float4*)(pa + d0);
        float4 Bv = *(const float4*)(pb + d0);
        float4 C = *(const float4*)(pc + d0);
        float m, df;
        m = (A.x + Bv.x + C.x) * third; df = z.x - m; acc += df * df;
        m = (A.y + Bv.y + C.y) * third; df = z.y - m; acc += df * df;
        m = (A.z + Bv.z + C.z) * third; df = z.z - m; acc += df * df;
        m = (A.w + Bv.w + C.w) * third; df = z.w - m; acc += df * df;
    }
    for (int off = 32; off; off >>= 1) acc += __shfl_xor(acc, off);
    if (lane == 0) rowsum[row] = acc;
}

// -------- push-loss row values (wave per row) --------
__global__ void k_push(const float* __restrict__ Z, const float* __restrict__ m_a_used,
                       const float* __restrict__ zn2, const float* __restrict__ scal_f,
                       float* __restrict__ rowpush) {
    int row = blockIdx.x * 4 + (threadIdx.x >> 6);
    int lane = threadIdx.x & 63;
    const float* zr = Z + (size_t)row * D_F;
    float acc = 0.f;
    for (int d0 = lane * 4; d0 < D_F; d0 += 256) {
        float4 z = *(const float4*)(zr + d0);
        float4 m = *(const float4*)(m_a_used + d0);
        acc += z.x * m.x + z.y * m.y + z.z * m.z + z.w * m.w;
    }
    for (int off = 32; off; off >>= 1) acc += __shfl_xor(acc, off);
    if (lane == 0) {
        float d2 = zn2[row] - 2.f * acc + scal_f[0];
        float dist = sqrtf(fmaxf(d2, 0.f));
        rowpush[row] = fmaxf(1.f - dist, 0.f);
    }
}

// -------- final combine --------
__global__ void k_final(const float* __restrict__ rowsum, const float* __restrict__ rowpush,
                        const int* __restrict__ scal, float* __restrict__ out) {
    __shared__ float red[1024];
    int tid = threadIdx.x;
    float s = 0.f;
    for (int i = tid; i < B_N; i += 1024) s += rowsum[i];
    red[tid] = s;
    __syncthreads();
    for (int off = 512; off; off >>= 1) {
        if (tid < off) red[tid] += red[tid + off];
        __syncthreads();
    }
    float pull = red[0] / ((float)B_N * (float)D_F);
    __syncthreads();
    float p = 0.f;
    for (int i = tid; i < B_N; i += 1024) p += rowpush[i];
    red[tid] = p;
    __syncthreads();
    for (int off = 512; off; off >>= 1) {
        if (tid < off) red[tid] += red[tid + off];
        __syncthreads();
    }
    if (tid == 0) {
        float lpush = (scal[1] > 0) ? (red[0] / (float)B_N) : 0.f;
        out[0] = pull + 0.5f * lpush;
    }
}

extern "C" void kernel_launch(void* const* d_in, const int* in_sizes, int n_in,
                              void* d_out, int out_size, void* d_ws, size_t ws_size,
                              hipStream_t stream) {
    const float* Z = (const float*)d_in[0];
    const int* g = (const int*)d_in[1];
    const float* P0 = (const float*)d_in[2];
    const float* ma_in = (const float*)d_in[4];
    float* out = (float*)d_out;

    float* ws = (float*)d_ws;
    float* Gram = ws;
    float* Dotf = ws;
    float* Dot = ws + (size_t)NGMAX * NGMAX;
    float* Pn = Dot + (size_t)K_P * NGMAX;
    float* zn2 = Pn + (size_t)K_P * D_F;
    float* pn2_0 = zn2 + B_N;
    float* pn2f = pn2_0 + K_P;
    float* anom_part = pn2f + K_P;
    float* m_a_used = anom_part + 32 * D_F;
    float* rowsum = m_a_used + D_F;
    float* rowpush = rowsum + B_N;
    float* scal_f = rowpush + B_N;
    int* gsteps = (int*)(scal_f + 16);
    int* cnt = gsteps + B_N;
    int* scal = cnt + K_P;
    int* winlist = scal + 16;
    int* clist = winlist + (size_t)K_P * NGMAX;
    unsigned short* Zhi = (unsigned short*)(clist + 8 * NGMAX);
    unsigned short* Zlo = Zhi + (size_t)B_N * D_F;
    unsigned short* P0hi = Zlo + (size_t)B_N * D_F;
    unsigned short* P0lo = P0hi + (size_t)K_P * D_F;
    unsigned short* Pnhi = P0lo + (size_t)K_P * D_F;
    unsigned short* Pnlo = Pnhi + (size_t)K_P * D_F;

    hipFuncSetAttribute((const void*)k_scan_tiled,
                        hipFuncAttributeMaxDynamicSharedMemorySize, SMEM_BYTES);

    k_prep<<<1, 1024, 0, stream>>>(g, gsteps, scal);
    k_split<<<(B_N * D_F / 4 + 255) / 256, 256, 0, stream>>>(Z, Zhi, Zlo, B_N * D_F / 4);
    k_split<<<(K_P * D_F / 4 + 255) / 256, 256, 0, stream>>>(P0, P0hi, P0lo, K_P * D_F / 4);
    k_rownorm<<<(B_N + 3) / 4, 256, 0, stream>>>(Z, zn2, B_N);
    k_rownorm<<<(K_P + 3) / 4, 256, 0, stream>>>(P0, pn2_0, K_P);
    k_colsum<<<dim3(D_F / 256, 32), 256, 0, stream>>>(Z, g, anom_part);
    k_fin_ma<<<1, 1024, 0, stream>>>(anom_part, ma_in, scal, m_a_used, scal_f);
    k_gemm_mfma<0><<<dim3(NGMAX / 64, (NGMAX + K_P) / 64), 256, 0, stream>>>(
        Zhi, Zlo, P0hi, P0lo, Pnhi, Pnlo, gsteps, scal, Gram, Dot, Dotf);
    k_scan_tiled<<<1, 512, SMEM_BYTES, stream>>>(Gram, Dot, pn2_0, zn2, gsteps, scal,
                                                 winlist, clist, cnt);
    k_mat<<<K_P, 256, 0, stream>>>(Z, P0, gsteps, winlist, cnt, Pn, Pnhi, Pnlo);
    k_rownorm<<<(K_P + 3) / 4, 256, 0, stream>>>(Pn, pn2f, K_P);
    k_gemm_mfma<1><<<dim3(K_P / 64, B_N / 64), 256, 0, stream>>>(
        Zhi, Zlo, P0hi, P0lo, Pnhi, Pnlo, gsteps, scal, Gram, Dot, Dotf);
    k_top3<<<B_N / 4, 256, 0, stream>>>(Dotf, pn2f, Z, Pn, rowsum);
    k_push<<<B_N / 4, 256, 0, stream>>>(Z, m_a_used, zn2, scal_f, rowpush);
    k_final<<<1, 1024, 0, stream>>>(rowsum, rowpush, scal, out);
}

// Round 17
// 1887.783 us; speedup vs baseline: 1.0190x; 1.0190x over previous
//
#include <hip/hip_runtime.h>
#include <math.h>

#define B_N 4096
#define D_F 2048
#define K_P 512
#define NGMAX 4096
#define MU 0.9f
#define OMU (1.0f - MU)
#define LOG2MU (-0.15200309344504997f)
#define FLTMAX 3.402823466e+38f
#define IMAX 0x7FFFFFFF
#define TILE 64
#define SDPITCH 513

// LDS carve (floats/ints) for scan
#define SMEM_FLOATS (64 * SDPITCH + 64 * 65 + 64 + 512)
#define SMEM_INTS (512 + 16)
#define SMEM_BYTES ((SMEM_FLOATS + SMEM_INTS) * 4)

typedef __attribute__((ext_vector_type(8))) short short8v;
typedef __attribute__((ext_vector_type(4))) float float4v;

__device__ __forceinline__ bool argless(float v1, int i1, float v2, int i2) {
    return (v1 < v2) || (v1 == v2 && i1 < i2);
}

// u32 DPP min-reduce: lane 63 holds the wave min; readlane broadcasts.
template <int CTRL>
__device__ __forceinline__ unsigned dppmin_u(unsigned v) {
    unsigned t = (unsigned)__builtin_amdgcn_update_dpp((int)v, (int)v, CTRL, 0xf, 0xf, false);
    return min(v, t);
}
__device__ __forceinline__ unsigned wave_min_u(unsigned v) {
    v = dppmin_u<0x111>(v);
    v = dppmin_u<0x112>(v);
    v = dppmin_u<0x114>(v);
    v = dppmin_u<0x118>(v);
    v = dppmin_u<0x142>(v);
    v = dppmin_u<0x143>(v);
    return (unsigned)__builtin_amdgcn_readlane((int)v, 63);
}

// -------- prep: compact gated indices, counts --------
__global__ void k_prep(const int* __restrict__ g, int* __restrict__ gsteps,
                       int* __restrict__ scal) {
    __shared__ int s[1024];
    __shared__ int base;
    int tid = threadIdx.x;
    if (tid == 0) base = 0;
    __syncthreads();
    for (int c = 0; c < 4; ++c) {
        int i = c * 1024 + tid;
        int gi = (g[i] != 0) ? 1 : 0;
        s[tid] = gi;
        __syncthreads();
        for (int off = 1; off < 1024; off <<= 1) {
            int v = (tid >= off) ? s[tid - off] : 0;
            __syncthreads();
            s[tid] += v;
            __syncthreads();
        }
        int pos = base + s[tid] - 1;
        if (gi) gsteps[pos] = i;
        __syncthreads();
        if (tid == 1023) base += s[1023];
        __syncthreads();
    }
    if (tid == 0) { scal[0] = base; scal[1] = B_N - base; }
}

// -------- fp32 -> bf16 hi/lo split (truncation; x == hi + lo + O(2^-14 x)) --------
__global__ void k_split(const float* __restrict__ src, unsigned short* __restrict__ hi,
                        unsigned short* __restrict__ lo, int n4) {
    int i = blockIdx.x * 256 + threadIdx.x;
    if (i >= n4) return;
    float4 v = ((const float4*)src)[i];
    float xs[4] = {v.x, v.y, v.z, v.w};
    unsigned short h[4], l[4];
#pragma unroll
    for (int q = 0; q < 4; ++q) {
        unsigned b = __float_as_uint(xs[q]);
        unsigned hb = b & 0xFFFF0000u;
        float lf = xs[q] - __uint_as_float(hb);
        h[q] = (unsigned short)(hb >> 16);
        l[q] = (unsigned short)(__float_as_uint(lf) >> 16);
    }
    ((ushort4*)hi)[i] = make_ushort4(h[0], h[1], h[2], h[3]);
    ((ushort4*)lo)[i] = make_ushort4(l[0], l[1], l[2], l[3]);
}

__device__ __forceinline__ void split_store(unsigned short* __restrict__ hi,
                                            unsigned short* __restrict__ lo,
                                            size_t idx, float4 v) {
    float xs[4] = {v.x, v.y, v.z, v.w};
    unsigned short h[4], l[4];
#pragma unroll
    for (int q = 0; q < 4; ++q) {
        unsigned b = __float_as_uint(xs[q]);
        unsigned hb = b & 0xFFFF0000u;
        float lf = xs[q] - __uint_as_float(hb);
        h[q] = (unsigned short)(hb >> 16);
        l[q] = (unsigned short)(__float_as_uint(lf) >> 16);
    }
    *(ushort4*)(hi + idx) = make_ushort4(h[0], h[1], h[2], h[3]);
    *(ushort4*)(lo + idx) = make_ushort4(l[0], l[1], l[2], l[3]);
}

// -------- row squared norms (wave per row) --------
__global__ void k_rownorm(const float* __restrict__ src, float* __restrict__ dst, int nrows) {
    int row = blockIdx.x * 4 + (threadIdx.x >> 6);
    int lane = threadIdx.x & 63;
    if (row >= nrows) return;
    const float* p = src + (size_t)row * D_F;
    float acc = 0.f;
    for (int d0 = lane * 4; d0 < D_F; d0 += 256) {
        float4 v = *(const float4*)(p + d0);
        acc += v.x * v.x + v.y * v.y + v.z * v.z + v.w * v.w;
    }
    for (int off = 32; off; off >>= 1) acc += __shfl_xor(acc, off);
    if (lane == 0) dst[row] = acc;
}

// -------- anomaly column sums (partials) --------
__global__ void k_colsum(const float* __restrict__ Z, const int* __restrict__ g,
                         float* __restrict__ anom_part) {
    int d = blockIdx.x * 256 + threadIdx.x;
    int rc = blockIdx.y;
    float acc = 0.f;
    int r0 = rc * 128;
    for (int r = r0; r < r0 + 128; ++r) {
        if (g[r] == 0) acc += Z[(size_t)r * D_F + d];
    }
    anom_part[(size_t)rc * D_F + d] = acc;
}

// -------- finalize m_a --------
__global__ void k_fin_ma(const float* __restrict__ anom_part, const float* __restrict__ ma_in,
                         const int* __restrict__ scal, float* __restrict__ m_a_used,
                         float* __restrict__ scal_f) {
    __shared__ float red[1024];
    int tid = threadIdx.x;
    int na = scal[1];
    float m2 = 0.f;
    for (int dd = tid; dd < D_F; dd += 1024) {
        float s = 0.f;
        for (int c = 0; c < 32; ++c) s += anom_part[(size_t)c * D_F + dd];
        float v = (na > 0) ? (s / (float)na) : ma_in[dd];
        m_a_used[dd] = v;
        m2 += v * v;
    }
    red[tid] = m2;
    __syncthreads();
    for (int off = 512; off; off >>= 1) {
        if (tid < off) red[tid] += red[tid + off];
        __syncthreads();
    }
    if (tid == 0) scal_f[0] = red[0];
}

// -------- MFMA GEMM (NT: C = A * B^T) via bf16 hi/lo split, 64x64 tile, BK=32 --------
template <int MODE>
__global__ __launch_bounds__(256)
void k_gemm_mfma(const unsigned short* __restrict__ Zhi, const unsigned short* __restrict__ Zlo,
                 const unsigned short* __restrict__ P0hi, const unsigned short* __restrict__ P0lo,
                 const unsigned short* __restrict__ Pnhi, const unsigned short* __restrict__ Pnlo,
                 const int* __restrict__ gsteps, const int* __restrict__ scal,
                 float* __restrict__ Gram, float* __restrict__ Dot, float* __restrict__ Dotf) {
    int ng = scal[0];
    int M = (MODE == 0) ? (ng + K_P) : B_N;
    int N = (MODE == 0) ? ng : K_P;
    int mb = blockIdx.y * 64, nb = blockIdx.x * 64;
    if (mb >= M || nb >= N) return;
    if (MODE == 0 && (mb + 64 <= ng) && (nb + 64 <= mb)) return;

    __shared__ __align__(16) unsigned short Ah[64][40];
    __shared__ __align__(16) unsigned short Al[64][40];
    __shared__ __align__(16) unsigned short Bh[64][40];
    __shared__ __align__(16) unsigned short Bl[64][40];
    __shared__ const unsigned short* rAh[64];
    __shared__ const unsigned short* rAl[64];
    __shared__ const unsigned short* rBh[64];
    __shared__ const unsigned short* rBl[64];

    int tid = threadIdx.x;
    if (tid < 64) {
        int gm = mb + tid;
        const unsigned short *ph = nullptr, *pl = nullptr;
        if (MODE == 0) {
            if (gm < ng) {
                size_t o = (size_t)gsteps[gm] * D_F;
                ph = Zhi + o; pl = Zlo + o;
            } else if (gm < ng + K_P) {
                size_t o = (size_t)(gm - ng) * D_F;
                ph = P0hi + o; pl = P0lo + o;
            }
        } else {
            if (gm < B_N) {
                size_t o = (size_t)gm * D_F;
                ph = Zhi + o; pl = Zlo + o;
            }
        }
        rAh[tid] = ph; rAl[tid] = pl;
    } else if (tid < 128) {
        int t = tid - 64;
        int gn = nb + t;
        const unsigned short *ph = nullptr, *pl = nullptr;
        if (MODE == 0) {
            if (gn < ng) {
                size_t o = (size_t)gsteps[gn] * D_F;
                ph = Zhi + o; pl = Zlo + o;
            }
        } else {
            if (gn < K_P) {
                size_t o = (size_t)gn * D_F;
                ph = Pnhi + o; pl = Pnlo + o;
            }
        }
        rBh[t] = ph; rBl[t] = pl;
    }
    __syncthreads();

    int lrow = tid >> 2, lk = (tid & 3) * 8;
    const unsigned short* pah = rAh[lrow];
    const unsigned short* pal = rAl[lrow];
    const unsigned short* pbh = rBh[lrow];
    const unsigned short* pbl = rBl[lrow];

    int wave = tid >> 6, lane = tid & 63;
    int wr = (wave >> 1) * 32, wc = (wave & 1) * 32;
    int fr = lane & 15, kg = lane >> 4;

    float4v acc00 = {0.f, 0.f, 0.f, 0.f}, acc01 = {0.f, 0.f, 0.f, 0.f};
    float4v acc10 = {0.f, 0.f, 0.f, 0.f}, acc11 = {0.f, 0.f, 0.f, 0.f};
    const int4 z4i = make_int4(0, 0, 0, 0);

    for (int k0 = 0; k0 < D_F; k0 += 32) {
        int4 vah = pah ? *(const int4*)(pah + k0 + lk) : z4i;
        int4 val = pal ? *(const int4*)(pal + k0 + lk) : z4i;
        int4 vbh = pbh ? *(const int4*)(pbh + k0 + lk) : z4i;
        int4 vbl = pbl ? *(const int4*)(pbl + k0 + lk) : z4i;
        __syncthreads();
        *(int4*)&Ah[lrow][lk] = vah;
        *(int4*)&Al[lrow][lk] = val;
        *(int4*)&Bh[lrow][lk] = vbh;
        *(int4*)&Bl[lrow][lk] = vbl;
        __syncthreads();

        short8v ah0 = *(const short8v*)&Ah[wr + fr][kg * 8];
        short8v ah1 = *(const short8v*)&Ah[wr + 16 + fr][kg * 8];
        short8v al0 = *(const short8v*)&Al[wr + fr][kg * 8];
        short8v al1 = *(const short8v*)&Al[wr + 16 + fr][kg * 8];
        short8v bh0 = *(const short8v*)&Bh[wc + fr][kg * 8];
        short8v bh1 = *(const short8v*)&Bh[wc + 16 + fr][kg * 8];
        short8v bl0 = *(const short8v*)&Bl[wc + fr][kg * 8];
        short8v bl1 = *(const short8v*)&Bl[wc + 16 + fr][kg * 8];

        acc00 = __builtin_amdgcn_mfma_f32_16x16x32_bf16(ah0, bh0, acc00, 0, 0, 0);
        acc00 = __builtin_amdgcn_mfma_f32_16x16x32_bf16(ah0, bl0, acc00, 0, 0, 0);
        acc00 = __builtin_amdgcn_mfma_f32_16x16x32_bf16(al0, bh0, acc00, 0, 0, 0);

        acc01 = __builtin_amdgcn_mfma_f32_16x16x32_bf16(ah0, bh1, acc01, 0, 0, 0);
        acc01 = __builtin_amdgcn_mfma_f32_16x16x32_bf16(ah0, bl1, acc01, 0, 0, 0);
        acc01 = __builtin_amdgcn_mfma_f32_16x16x32_bf16(al0, bh1, acc01, 0, 0, 0);

        acc10 = __builtin_amdgcn_mfma_f32_16x16x32_bf16(ah1, bh0, acc10, 0, 0, 0);
        acc10 = __builtin_amdgcn_mfma_f32_16x16x32_bf16(ah1, bl0, acc10, 0, 0, 0);
        acc10 = __builtin_amdgcn_mfma_f32_16x16x32_bf16(al1, bh0, acc10, 0, 0, 0);

        acc11 = __builtin_amdgcn_mfma_f32_16x16x32_bf16(ah1, bh1, acc11, 0, 0, 0);
        acc11 = __builtin_amdgcn_mfma_f32_16x16x32_bf16(ah1, bl1, acc11, 0, 0, 0);
        acc11 = __builtin_amdgcn_mfma_f32_16x16x32_bf16(al1, bh1, acc11, 0, 0, 0);
    }

#pragma unroll
    for (int fm = 0; fm < 2; ++fm) {
#pragma unroll
        for (int i = 0; i < 4; ++i) {
            int grow = mb + wr + fm * 16 + kg * 4 + i;
            if (grow >= M) continue;
            float* crow;
            if (MODE == 0)
                crow = (grow < ng) ? (Gram + (size_t)grow * NGMAX)
                                   : (Dot + (size_t)(grow - ng) * NGMAX);
            else
                crow = Dotf + (size_t)grow * K_P;
#pragma unroll
            for (int fn = 0; fn < 2; ++fn) {
                int gcol = nb + wc + fn * 16 + fr;
                if (gcol >= N) continue;
                float v;
                if (fm == 0 && fn == 0) v = acc00[i];
                else if (fm == 0 && fn == 1) v = acc01[i];
                else if (fm == 1 && fn == 0) v = acc10[i];
                else v = acc11[i];
                crow[gcol] = v;
            }
        }
    }
}

// -------- tiled sequential scan: packed-key argmin + batched corrections --------
__global__ __launch_bounds__(512, 1)
void k_scan_tiled(const float* __restrict__ Gram, const float* __restrict__ Dot,
                  const float* __restrict__ pn2_0, const float* __restrict__ zn2,
                  const int* __restrict__ gsteps, const int* __restrict__ scal,
                  int* __restrict__ winlist, int* __restrict__ clist,
                  int* __restrict__ cnt_out) {
    extern __shared__ char smem_raw[];
    float* sdot = (float*)smem_raw;             // [64][SDPITCH] transposed: sdot[x][k]
    float* sgram = sdot + 64 * SDPITCH;         // [64][65]
    float* szn2 = sgram + 64 * 65;              // [64]
    float* sscale = szn2 + 64;                  // [512] mu^rowcnt per row
    int* rowcnt = (int*)(sscale + 512);         // [512] global win counts
    int* listlen = rowcnt + 512;                // [8] per-wave correction-list lengths

    int tid = threadIdx.x;
    int lane = tid & 63;
    int wave = tid >> 6;
    int ng = scal[0];

    rowcnt[tid] = 0;
    if (tid < 8) listlen[tid] = 0;
    __syncthreads();

    // wave-0 lane-private state: lane owns prototypes k = r*64 + lane
    float pn2r[8];
    unsigned idxp[8];
    if (wave == 0) {
#pragma unroll
        for (int r = 0; r < 8; ++r) {
            pn2r[r] = pn2_0[r * 64 + lane];
            idxp[r] = (unsigned)((r << 6) | lane);
        }
    }

    int ntiles = (ng + TILE - 1) / TILE;
    for (int T = 0; T < ntiles; ++T) {
        int j0 = T * TILE;
        int tlen = min(TILE, ng - j0);

        // per-row scale (same-wave write/read: thread tid serves wave tid>>6)
        sscale[tid] = exp2f((float)rowcnt[tid] * LOG2MU);

        // ---- stage Dot0 tile (transposed) with mu^c scale fused ----
        {
            const float* basep = Dot + (size_t)(wave * 64) * NGMAX + j0 + lane;
            float* sb = sdot + lane * SDPITCH + wave * 64;
            const float* ss = sscale + wave * 64;
#pragma unroll 16
            for (int rr = 0; rr < 64; ++rr) {
                sb[rr] = basep[(size_t)rr * NGMAX] * ss[rr];
            }
        }
        // ---- corrections: wave streams its own flat list, batched (MLP=8) ----
        {
            int len = listlen[wave];
            const int* cl = clist + (size_t)wave * NGMAX;
            int i = 0;
            for (; i + 8 <= len; i += 8) {
                int a[8];
#pragma unroll
                for (int q = 0; q < 8; ++q) a[q] = cl[i + q];
                float gv[8];
#pragma unroll
                for (int q = 0; q < 8; ++q) {
                    int t = (a[q] >> 20) & 4095;
                    gv[q] = Gram[(size_t)t * NGMAX + j0 + lane];
                }
                float wq[8];
#pragma unroll
                for (int q = 0; q < 8; ++q) {
                    int row = a[q] & 511;
                    int gq = (a[q] >> 9) & 2047;
                    int c = rowcnt[row];
                    wq[q] = OMU * exp2f((float)(c - 1 - gq) * LOG2MU);
                }
#pragma unroll
                for (int q = 0; q < 8; ++q) {
                    int row = a[q] & 511;
                    sdot[lane * SDPITCH + row] += wq[q] * gv[q];
                }
            }
            for (; i < len; ++i) {
                int a = cl[i];
                int row = a & 511;
                int gq = (a >> 9) & 2047;
                int t = (a >> 20) & 4095;
                int c = rowcnt[row];
                float wqs = OMU * exp2f((float)(c - 1 - gq) * LOG2MU);
                float gv = Gram[(size_t)t * NGMAX + j0 + lane];
                sdot[lane * SDPITCH + row] += wqs * gv;
            }
        }
        // gram diag block + zn2
        {
            int t = tid >> 3, xo = (tid & 7) * 8;
            const float* src = Gram + (size_t)(j0 + t) * NGMAX + j0 + xo;
            float4 a = *(const float4*)(src);
            float4 b = *(const float4*)(src + 4);
            float* dst = sgram + t * 65 + xo;
            dst[0] = a.x; dst[1] = a.y; dst[2] = a.z; dst[3] = a.w;
            dst[4] = b.x; dst[5] = b.y; dst[6] = b.z; dst[7] = b.w;
        }
        if (tid < TILE) {
            szn2[tid] = (tid < tlen) ? zn2[gsteps[j0 + tid]] : 0.f;
        }
        __syncthreads();

        // ---- phase S (wave 0 only) ----
        if (wave == 0) {
            float d8[8];
#pragma unroll
            for (int r = 0; r < 8; ++r) d8[r] = sdot[r * 64 + lane];  // col 0
            float z2c = szn2[0];
            float gnc = sgram[1];  // G[0][1]
            int stw_reg = 0;
            // deferred-RMW state: write of step j lands at top of step j+1
            int pend_addr = -1;
            float pend_old = 0.f, pend_g = 0.f;

            for (int jl = 0; jl < tlen; ++jl) {
                // (0) flush previous step's RMW write (before any sdot read below)
                if (pend_addr >= 0) {
                    sdot[pend_addr] = MU * pend_old + OMU * pend_g;
                }
                // (1) prefetch next column + scalars + RMW gram operand
                float pv[8];
                float nz2 = 0.f, ngn = 0.f;
                const bool hn = (jl + 1 < tlen);
                int xr = jl + 2 + lane;
                float grmw = sgram[jl * 65 + (xr < 64 ? xr : 63)];
                if (hn) {
                    const float* cb = sdot + (jl + 1) * SDPITCH;
#pragma unroll
                    for (int r = 0; r < 8; ++r) pv[r] = cb[r * 64 + lane];
                    nz2 = szn2[jl + 1];
                    ngn = sgram[(jl + 1) * 65 + (jl + 2)];
                } else {
#pragma unroll
                    for (int r = 0; r < 8; ++r) pv[r] = 0.f;
                }

                // (2) packed-key argmin
                unsigned kk[8];
#pragma unroll
                for (int r = 0; r < 8; ++r) {
                    float v = (pn2r[r] + z2c) - 2.f * d8[r];
                    kk[r] = (__float_as_uint(v) & 0xFFFFFE00u) | idxp[r];
                }
                unsigned a01 = min(kk[0], kk[1]), a23 = min(kk[2], kk[3]);
                unsigned a45 = min(kk[4], kk[5]), a67 = min(kk[6], kk[7]);
                unsigned km = wave_min_u(min(min(a01, a23), min(a45, a67)));
                int ks = (int)(km & 511u);
                int wlane = ks & 63, wr = ks >> 6;

                // (3) issue the RMW read ASAP; consumed at next iteration's flush
                bool do_rmw = (xr < tlen);
                int rmw_addr = xr * SDPITCH + ks;
                float rmw_old = 0.f;
                if (do_rmw) rmw_old = sdot[rmw_addr];

                stw_reg = (lane == jl) ? ks : stw_reg;

                bool mine = (lane == wlane);
#pragma unroll
                for (int r = 0; r < 8; ++r) {
                    if (mine && r == wr) {
                        pn2r[r] = MU * MU * pn2r[r] + 2.f * MU * OMU * d8[r] + OMU * OMU * z2c;
                        pv[r] = MU * pv[r] + OMU * gnc;
                    }
                }

                // shift register pipeline
#pragma unroll
                for (int r = 0; r < 8; ++r) d8[r] = pv[r];
                z2c = nz2; gnc = ngn;

                // (4) arm deferred write
                pend_addr = do_rmw ? rmw_addr : -1;
                pend_old = rmw_old;
                pend_g = grmw;
            }
            if (pend_addr >= 0) {
                sdot[pend_addr] = MU * pend_old + OMU * pend_g;
            }

            // ---- post-pass: ranks, winlist append, per-wave correction lists ----
            int wj = stw_reg;
            bool valid = (lane < tlen);
            int myL = wj >> 6;
            int rank = 0, mrow = 0, lpos = 0, lcnt = 0;
            for (int i = 0; i < tlen; ++i) {
                int wi = __builtin_amdgcn_readlane(wj, i);
                if (valid && wi == wj) {
                    mrow++;
                    if (i < lane) rank++;
                }
                if (valid && (wi >> 6) == myL) {
                    lcnt++;
                    if (i < lane) lpos++;
                }
            }
            bool first = valid && (rank == 0);
            bool firstL = valid && (lpos == 0);
            int base = rowcnt[wj];      // read by all lanes before any update below
            int lbase = listlen[myL];
            if (valid) {
                int gq = base + rank;
                winlist[(size_t)wj * NGMAX + gq] = j0 + lane;
                clist[(size_t)myL * NGMAX + lbase + lpos] =
                    wj | (gq << 9) | ((j0 + lane) << 20);
            }
            if (first) rowcnt[wj] += mrow;
            if (firstL) listlen[myL] += lcnt;
        }
        __syncthreads();
    }

    cnt_out[tid] = rowcnt[tid];
}

// -------- materialize final prototypes via win lists (block per prototype) --------
__global__ void k_mat(const float* __restrict__ Z, const float* __restrict__ P0,
                      const int* __restrict__ gsteps, const int* __restrict__ winlist,
                      const int* __restrict__ cnt, float* __restrict__ Pn,
                      unsigned short* __restrict__ Pnhi, unsigned short* __restrict__ Pnlo) {
    int k = blockIdx.x;
    int tid = threadIdx.x;
    int c = cnt[k];
    float bw = exp2f((float)c * LOG2MU);
    const float4* p0r = (const float4*)(P0 + (size_t)k * D_F);
    float4 a0 = p0r[tid], a1 = p0r[tid + 256];
    a0.x *= bw; a0.y *= bw; a0.z *= bw; a0.w *= bw;
    a1.x *= bw; a1.y *= bw; a1.z *= bw; a1.w *= bw;
    const int* wl = winlist + (size_t)k * NGMAX;
    float w = OMU;
    for (int q = c - 1; q >= 0; --q) {
        int t = wl[q];
        const float4* zr = (const float4*)(Z + (size_t)gsteps[t] * D_F);
        float4 z0 = zr[tid], z1 = zr[tid + 256];
        a0.x += w * z0.x; a0.y += w * z0.y; a0.z += w * z0.z; a0.w += w * z0.w;
        a1.x += w * z1.x; a1.y += w * z1.y; a1.z += w * z1.z; a1.w += w * z1.w;
        w *= MU;
    }
    float4* pnr = (float4*)(Pn + (size_t)k * D_F);
    pnr[tid] = a0;
    pnr[tid + 256] = a1;
    split_store(Pnhi, Pnlo, (size_t)k * D_F + (size_t)tid * 4, a0);
    split_store(Pnhi, Pnlo, (size_t)k * D_F + (size_t)(tid + 256) * 4, a1);
}

// -------- top-3 nearest + pull-loss row sums (wave per row) --------
__global__ void k_top3(const float* __restrict__ Dotf, const float* __restrict__ pn2f,
                       const float* __restrict__ Z, const float* __restrict__ Pn,
                       float* __restrict__ rowsum) {
    int row = blockIdx.x * 4 + (threadIdx.x >> 6);
    int lane = threadIdx.x & 63;
    float bv0 = FLTMAX, bv1 = FLTMAX, bv2 = FLTMAX;
    int bi0 = IMAX, bi1 = IMAX, bi2 = IMAX;
    for (int t = 0; t < 8; ++t) {
        int k = lane + 64 * t;
        float v = pn2f[k] - 2.f * Dotf[(size_t)row * K_P + k];
        if (argless(v, k, bv0, bi0)) {
            bv2 = bv1; bi2 = bi1; bv1 = bv0; bi1 = bi0; bv0 = v; bi0 = k;
        } else if (argless(v, k, bv1, bi1)) {
            bv2 = bv1; bi2 = bi1; bv1 = v; bi1 = k;
        } else if (argless(v, k, bv2, bi2)) {
            bv2 = v; bi2 = k;
        }
    }
    for (int off = 32; off; off >>= 1) {
        float a0 = bv0, a1 = bv1, a2 = bv2;
        int x0 = bi0, x1 = bi1, x2 = bi2;
        float b0 = __shfl_xor(bv0, off), b1 = __shfl_xor(bv1, off), b2 = __shfl_xor(bv2, off);
        int y0 = __shfl_xor(bi0, off), y1 = __shfl_xor(bi1, off), y2 = __shfl_xor(bi2, off);
        float nv[3]; int ni[3];
#pragma unroll
        for (int s = 0; s < 3; ++s) {
            bool ta = argless(a0, x0, b0, y0);
            nv[s] = ta ? a0 : b0;
            ni[s] = ta ? x0 : y0;
            if (ta) { a0 = a1; x0 = x1; a1 = a2; x1 = x2; a2 = FLTMAX; x2 = IMAX; }
            else    { b0 = b1; y0 = y1; b1 = b2; y1 = y2; b2 = FLTMAX; y2 = IMAX; }
        }
        bv0 = nv[0]; bv1 = nv[1]; bv2 = nv[2];
        bi0 = ni[0]; bi1 = ni[1]; bi2 = ni[2];
    }
    const float* pa = Pn + (size_t)bi0 * D_F;
    const float* pb = Pn + (size_t)bi1 * D_F;
    const float* pc = Pn + (size_t)bi2 * D_F;
    const float* zr = Z + (size_t)row * D_F;
    const float third = 1.f / 3.f;
    float acc = 0.f;
    for (int d0 = lane * 4; d0 < D_F; d0 += 256) {
        float4 z = *(const float4*)(zr + d0);
        float4 A = *(const float4*)(pa + d0);
        float4 Bv = *(const float4*)(pb + d0);
        float4 C = *(const float4*)(pc + d0);
        float m, df;
        m = (A.x + Bv.x + C.x) * third; df = z.x - m; acc += df * df;
        m = (A.y + Bv.y + C.y) * third; df = z.y - m; acc += df * df;
        m = (A.z + Bv.z + C.z) * third; df = z.z - m; acc += df * df;
        m = (A.w + Bv.w + C.w) * third; df = z.w - m; acc += df * df;
    }
    for (int off = 32; off; off >>= 1) acc += __shfl_xor(acc, off);
    if (lane == 0) rowsum[row] = acc;
}

// -------- push-loss row values (wave per row) --------
__global__ void k_push(const float* __restrict__ Z, const float* __restrict__ m_a_used,
                       const float* __restrict__ zn2, const float* __restrict__ scal_f,
                       float* __restrict__ rowpush) {
    int row = blockIdx.x * 4 + (threadIdx.x >> 6);
    int lane = threadIdx.x & 63;
    const float* zr = Z + (size_t)row * D_F;
    float acc = 0.f;
    for (int d0 = lane * 4; d0 < D_F; d0 += 256) {
        float4 z = *(const float4*)(zr + d0);
        float4 m = *(const float4*)(m_a_used + d0);
        acc += z.x * m.x + z.y * m.y + z.z * m.z + z.w * m.w;
    }
    for (int off = 32; off; off >>= 1) acc += __shfl_xor(acc, off);
    if (lane == 0) {
        float d2 = zn2[row] - 2.f * acc + scal_f[0];
        float dist = sqrtf(fmaxf(d2, 0.f));
        rowpush[row] = fmaxf(1.f - dist, 0.f);
    }
}

// -------- final combine --------
__global__ void k_final(const float* __restrict__ rowsum, const float* __restrict__ rowpush,
                        const int* __restrict__ scal, float* __restrict__ out) {
    __shared__ float red[1024];
    int tid = threadIdx.x;
    float s = 0.f;
    for (int i = tid; i < B_N; i += 1024) s += rowsum[i];
    red[tid] = s;
    __syncthreads();
    for (int off = 512; off; off >>= 1) {
        if (tid < off) red[tid] += red[tid + off];
        __syncthreads();
    }
    float pull = red[0] / ((float)B_N * (float)D_F);
    __syncthreads();
    float p = 0.f;
    for (int i = tid; i < B_N; i += 1024) p += rowpush[i];
    red[tid] = p;
    __syncthreads();
    for (int off = 512; off; off >>= 1) {
        if (tid < off) red[tid] += red[tid + off];
        __syncthreads();
    }
    if (tid == 0) {
        float lpush = (scal[1] > 0) ? (red[0] / (float)B_N) : 0.f;
        out[0] = pull + 0.5f * lpush;
    }
}

extern "C" void kernel_launch(void* const* d_in, const int* in_sizes, int n_in,
                              void* d_out, int out_size, void* d_ws, size_t ws_size,
                              hipStream_t stream) {
    const float* Z = (const float*)d_in[0];
    const int* g = (const int*)d_in[1];
    const float* P0 = (const float*)d_in[2];
    const float* ma_in = (const float*)d_in[4];
    float* out = (float*)d_out;

    float* ws = (float*)d_ws;
    float* Gram = ws;                                   // 16M floats
    float* Dotf = ws;                                   // overlaps Gram (Gram dead by then)
    float* Dot = ws + (size_t)NGMAX * NGMAX;            // 512*4096 (read-only after GEMM)
    float* Pn = Dot + (size_t)K_P * NGMAX;              // 512*2048
    float* zn2 = Pn + (size_t)K_P * D_F;                // 4096
    float* pn2_0 = zn2 + B_N;                           // 512
    float* pn2f = pn2_0 + K_P;                          // 512
    float* anom_part = pn2f + K_P;                      // 32*2048
    float* m_a_used = anom_part + 32 * D_F;             // 2048
    float* rowsum = m_a_used + D_F;                     // 4096
    float* rowpush = rowsum + B_N;                      // 4096
    float* scal_f = rowpush + B_N;                      // 16
    int* gsteps = (int*)(scal_f + 16);                  // 4096
    int* cnt = gsteps + B_N;                            // 512
    int* scal = cnt + K_P;                              // 16
    int* winlist = scal + 16;                           // 512*4096 (8 MB)
    int* clist = winlist + (size_t)K_P * NGMAX;         // 8*4096 ints
    unsigned short* Zhi = (unsigned short*)(clist + 8 * NGMAX);   // 16 MB
    unsigned short* Zlo = Zhi + (size_t)B_N * D_F;                // 16 MB
    unsigned short* P0hi = Zlo + (size_t)B_N * D_F;               // 2 MB
    unsigned short* P0lo = P0hi + (size_t)K_P * D_F;
    unsigned short* Pnhi = P0lo + (size_t)K_P * D_F;
    unsigned short* Pnlo = Pnhi + (size_t)K_P * D_F;

    hipFuncSetAttribute((const void*)k_scan_tiled,
                        hipFuncAttributeMaxDynamicSharedMemorySize, SMEM_BYTES);

    k_prep<<<1, 1024, 0, stream>>>(g, gsteps, scal);
    k_split<<<(B_N * D_F / 4 + 255) / 256, 256, 0, stream>>>(Z, Zhi, Zlo, B_N * D_F / 4);
    k_split<<<(K_P * D_F / 4 + 255) / 256, 256, 0, stream>>>(P0, P0hi, P0lo, K_P * D_F / 4);
    k_rownorm<<<(B_N + 3) / 4, 256, 0, stream>>>(Z, zn2, B_N);
    k_rownorm<<<(K_P + 3) / 4, 256, 0, stream>>>(P0, pn2_0, K_P);
    k_colsum<<<dim3(D_F / 256, 32), 256, 0, stream>>>(Z, g, anom_part);
    k_fin_ma<<<1, 1024, 0, stream>>>(anom_part, ma_in, scal, m_a_used, scal_f);
    k_gemm_mfma<0><<<dim3(NGMAX / 64, (NGMAX + K_P) / 64), 256, 0, stream>>>(
        Zhi, Zlo, P0hi, P0lo, Pnhi, Pnlo, gsteps, scal, Gram, Dot, Dotf);
    k_scan_tiled<<<1, 512, SMEM_BYTES, stream>>>(Gram, Dot, pn2_0, zn2, gsteps, scal,
                                                 winlist, clist, cnt);
    k_mat<<<K_P, 256, 0, stream>>>(Z, P0, gsteps, winlist, cnt, Pn, Pnhi, Pnlo);
    k_rownorm<<<(K_P + 3) / 4, 256, 0, stream>>>(Pn, pn2f, K_P);
    k_gemm_mfma<1><<<dim3(K_P / 64, B_N / 64), 256, 0, stream>>>(
        Zhi, Zlo, P0hi, P0lo, Pnhi, Pnlo, gsteps, scal, Gram, Dot, Dotf);
    k_top3<<<B_N / 4, 256, 0, stream>>>(Dotf, pn2f, Z, Pn, rowsum);
    k_push<<<B_N / 4, 256, 0, stream>>>(Z, m_a_used, zn2, scal_f, rowpush);
    k_final<<<1, 1024, 0, stream>>>(rowsum, rowpush, scal, out);
}